// Round 7
// baseline (401.204 us; speedup 1.0000x reference)
//
#include <hip/hip_runtime.h>
#include <hip/hip_bf16.h>

#define SLEN  256
#define BSZ   8
#define NHEAD 16
#define DHEAD 64
#define INDIM 1024
#define LN_EPS 1e-5f

typedef __attribute__((ext_vector_type(4))) float f32x4;
typedef __attribute__((ext_vector_type(8))) short bf16x8;

__device__ __forceinline__ int f_as_i(float f) { union { float f; int i; } u; u.f = f; return u.i; }
__device__ __forceinline__ float i_as_f(int i) { union { float f; int i; } u; u.i = i; return u.f; }

__device__ inline unsigned short f2bf(float x) {
  __hip_bfloat16 b = __float2bfloat16(x);
  union { __hip_bfloat16 b; unsigned short u; } cv;
  cv.b = b;
  return cv.u;
}

template <int CTRL>
__device__ __forceinline__ float dpp0(float x) {
  return i_as_f(__builtin_amdgcn_update_dpp(0, f_as_i(x), CTRL, 0xF, 0xF, true));
}
// adjacent-lane pair swap: quad_perm [1,0,3,2]
__device__ __forceinline__ float pair_other(float x) { return dpp0<0xB1>(x); }

__device__ __forceinline__ float wave_sum64(float v) {
  v += dpp0<0x111>(v);
  v += dpp0<0x112>(v);
  v += dpp0<0x114>(v);
  v += dpp0<0x118>(v);
  v += dpp0<0x142>(v);  // row_bcast:15
  v += dpp0<0x143>(v);  // row_bcast:31
  return i_as_f(__builtin_amdgcn_readlane(f_as_i(v), 63));
}

// --------------------------------------------------------------------------
// Fused kernel (512 threads/block):
//   blocks 0..127     : SRWM scan, one chain per block, 8 waves
//   blocks 128..639   : out_w fp32->bf16
//   blocks 640..2687  : LN stats + write h_ln into d_out
// --------------------------------------------------------------------------
__global__ __launch_bounds__(512, 1) void scan_prep_k(
    const float* __restrict__ h,
    const float* __restrict__ Wy0,
    const float* __restrict__ Wq0,
    const float* __restrict__ Wk0,
    const float* __restrict__ wb0,
    const float* __restrict__ outw,
    const float* __restrict__ gamma,
    const float* __restrict__ lbeta,
    unsigned short* __restrict__ outw_bf,
    float* __restrict__ outp,
    unsigned short* __restrict__ ys_bf) {
  const int bid = blockIdx.x;
  const int tid = threadIdx.x;

  if (bid >= 128) {
    const int pb = bid - 128;
    if (pb < 512) {
      int i = (pb * 512 + tid) * 4;
      float4 v = *(const float4*)(outw + i);
      ushort4 o;
      o.x = f2bf(v.x); o.y = f2bf(v.y); o.z = f2bf(v.z); o.w = f2bf(v.w);
      *(ushort4*)(outw_bf + i) = o;
    } else {
      int r = pb - 512;  // 0..2047
      const float* row = h + (size_t)r * INDIM;
      float2 v = *(const float2*)(row + tid * 2);
      float s  = v.x + v.y;
      float s2 = v.x * v.x + v.y * v.y;
      s  = wave_sum64(s);
      s2 = wave_sum64(s2);
      __shared__ float ls[8], ls2[8], sstat[2];
      int wvv = tid >> 6;
      if ((tid & 63) == 0) { ls[wvv] = s; ls2[wvv] = s2; }
      __syncthreads();
      if (tid == 0) {
        float S = 0.f, S2 = 0.f;
        #pragma unroll
        for (int i2 = 0; i2 < 8; ++i2) { S += ls[i2]; S2 += ls2[i2]; }
        float mu = S * (1.0f / INDIM);
        float var = S2 * (1.0f / INDIM) - mu * mu;
        sstat[0] = mu;
        sstat[1] = rsqrtf(var + LN_EPS);
      }
      __syncthreads();
      float mu = sstat[0], rs = sstat[1];
      float2 g2 = *(const float2*)(gamma + tid * 2);
      float2 b2 = *(const float2*)(lbeta + tid * 2);
      float2 o;
      o.x = (v.x - mu) * rs * g2.x + b2.x;
      o.y = (v.y - mu) * rs * g2.y + b2.y;
      *(float2*)(outp + (size_t)r * INDIM + tid * 2) = o;
    }
    return;
  }

  // ---------------- SRWM scan ----------------
  // waves 0..5: matrix waves (m = wv>>1: 0=Wy,1=Wq,2=Wk; half = wv&1)
  //   lane pair (2p,2p+1) owns row r=half*32+p; lane&1 picks 32-col half.
  //   x_t loaded from GLOBAL at phase top (L2-resident, latency hidden by
  //   the dv/update section before the matvec consumes it).
  // wave 6: wb / beta.  wave 7: barrier-idle (keeps barrier counts equal).
  const int chain = bid;
  const int b    = chain >> 4;
  const int head = chain & 15;
  const int wv   = __builtin_amdgcn_readfirstlane(tid >> 6);
  const int lane = tid & 63;

  // packed q,k: dword per row = (bf16(eq) low) | (bf16(ek) high)
  __shared__ __align__(16) unsigned int qkp[2][64];
  // meta: [0..3] = ssub{q0,q1,k0,k1}, [4..7] = beta
  __shared__ __align__(16) float meta[2][8];

  if (wv < 6) {
    const int m    = wv >> 1;
    const int half = wv & 1;
    const int r    = half * 32 + (lane >> 1);
    const int j0   = (lane & 1) * 32;
    const float* Wsel = (m == 0) ? Wy0 : ((m == 1) ? Wq0 : Wk0);
    const float* wrow = Wsel + (size_t)head * DHEAD * DHEAD + (size_t)r * DHEAD + j0;
    float wt[32];
    #pragma unroll
    for (int g = 0; g < 8; ++g) {
      float4 t4 = *(const float4*)(wrow + g * 4);
      wt[g * 4] = t4.x; wt[g * 4 + 1] = t4.y; wt[g * 4 + 2] = t4.z; wt[g * 4 + 3] = t4.w;
    }
    const float* xg0 = h + (size_t)b * INDIM + head * DHEAD + j0;

    for (int t = 0; t < SLEN; ++t) {
      const int buf = t & 1, bp = buf ^ 1;
      // issue x_t loads now; consumed by the matvec after dv/update
      float4 xf[8];
      {
        const float* xg = xg0 + (size_t)t * (BSZ * INDIM);
        #pragma unroll
        for (int g = 0; g < 8; ++g) xf[g] = *(const float4*)(xg + g * 4);
      }
      if (t > 0) {
        float4 ssb = *(const float4*)(&meta[bp][0]);
        float4 btb = *(const float4*)(&meta[bp][4]);
        uint4 kp[8];
        float dq0 = 0.f, dq1 = 0.f, dq2 = 0.f, dq3 = 0.f;
        float dk0 = 0.f, dk1 = 0.f, dk2 = 0.f, dk3 = 0.f;
        #pragma unroll
        for (int g = 0; g < 8; ++g) {
          uint4 p = *(const uint4*)(&qkp[bp][j0 + g * 4]);
          kp[g] = p;
          dq0 += wt[g * 4]     * i_as_f((int)(p.x << 16));
          dk0 += wt[g * 4]     * i_as_f((int)(p.x & 0xFFFF0000u));
          dq1 += wt[g * 4 + 1] * i_as_f((int)(p.y << 16));
          dk1 += wt[g * 4 + 1] * i_as_f((int)(p.y & 0xFFFF0000u));
          dq2 += wt[g * 4 + 2] * i_as_f((int)(p.z << 16));
          dk2 += wt[g * 4 + 2] * i_as_f((int)(p.z & 0xFFFF0000u));
          dq3 += wt[g * 4 + 3] * i_as_f((int)(p.w << 16));
          dk3 += wt[g * 4 + 3] * i_as_f((int)(p.w & 0xFFFF0000u));
        }
        float rq = __fdividef(1.f, ssb.x + ssb.y);
        float rk = __fdividef(1.f, ssb.z + ssb.w);
        float dv = rq * ((dq0 + dq1) + (dq2 + dq3)) - rk * ((dk0 + dk1) + (dk2 + dk3));
        dv += pair_other(dv);
        float bet = (m == 0) ? btb.x : ((m == 1) ? btb.y : btb.z);
        float c = bet * dv * rk;
        #pragma unroll
        for (int g = 0; g < 8; ++g) {
          uint4 p = kp[g];
          wt[g * 4]     += c * i_as_f((int)(p.x & 0xFFFF0000u));
          wt[g * 4 + 1] += c * i_as_f((int)(p.y & 0xFFFF0000u));
          wt[g * 4 + 2] += c * i_as_f((int)(p.z & 0xFFFF0000u));
          wt[g * 4 + 3] += c * i_as_f((int)(p.w & 0xFFFF0000u));
        }
      }
      // matvec v = W_t x_t
      float a0 = 0.f, a1 = 0.f, a2 = 0.f, a3 = 0.f;
      #pragma unroll
      for (int g = 0; g < 8; ++g) {
        a0 += wt[g * 4]     * xf[g].x;
        a1 += wt[g * 4 + 1] * xf[g].y;
        a2 += wt[g * 4 + 2] * xf[g].z;
        a3 += wt[g * 4 + 3] * xf[g].w;
      }
      float v = (a0 + a1) + (a2 + a3);
      v += pair_other(v);

      if (m == 0) {
        if (!(lane & 1))
          ys_bf[(size_t)(t * BSZ + b) * INDIM + head * DHEAD + r] = f2bf(v);
      } else {
        float e = __expf(v);  // logits bounded; no max-subtract
        unsigned int eu = ((unsigned int)f_as_i(e)) & 0xFFFF0000u;
        if (!(lane & 1))
          ((unsigned short*)&qkp[buf][r])[m - 1] = (unsigned short)(eu >> 16);
        float sh = wave_sum64(i_as_f((int)eu)) * 0.5f;  // pair-duplicated rows
        if (lane == 0) meta[buf][(m - 1) * 2 + half] = sh;
      }
      __syncthreads();
    }
  } else if (wv == 6) {
    // wb / beta wave
    const float* wbrow = wb0 + (size_t)head * DHEAD * 4 + lane * 4;
    float4 wbv = *(const float4*)wbrow;
    const float* xl = h + (size_t)b * INDIM + head * DHEAD + lane;
    float xv = xl[0];
    float xn = xl[(size_t)BSZ * INDIM];
    float b3prev = 0.f;

    for (int t = 0; t < SLEN; ++t) {
      const int buf = t & 1, bp = buf ^ 1;
      if (t > 0) {
        unsigned int d = qkp[bp][lane];
        float4 ssb = *(const float4*)(&meta[bp][0]);
        float rq = __fdividef(1.f, ssb.x + ssb.y);
        float rk = __fdividef(1.f, ssb.z + ssb.w);
        float qv = rq * i_as_f((int)(d << 16));
        float kv = rk * i_as_f((int)(d & 0xFFFF0000u));
        float qmk = qv - kv;
        float g0 = wave_sum64(wbv.x * qmk);
        float g1 = wave_sum64(wbv.y * qmk);
        float g2 = wave_sum64(wbv.z * qmk);
        float g3 = wave_sum64(wbv.w * qmk);
        float cl = b3prev * kv;
        wbv.x += cl * g0; wbv.y += cl * g1; wbv.z += cl * g2; wbv.w += cl * g3;
      }
      // beta_t from updated wb and x_t
      float p0 = wave_sum64(wbv.x * xv);
      float p1 = wave_sum64(wbv.y * xv);
      float p2 = wave_sum64(wbv.z * xv);
      float p3 = wave_sum64(wbv.w * xv);
      float b0 = __fdividef(1.f, 1.f + __expf(-p0));
      float b1 = __fdividef(1.f, 1.f + __expf(-p1));
      float b2 = __fdividef(1.f, 1.f + __expf(-p2));
      float b3 = __fdividef(1.f, 1.f + __expf(-p3));
      if (lane == 0) *(float4*)(&meta[buf][4]) = (float4){b0, b1, b2, b3};
      b3prev = b3;
      xv = xn;
      if (t + 2 < SLEN) xn = xl[(size_t)(t + 2) * BSZ * INDIM];
      __syncthreads();
    }
  } else {
    // wave 7: barrier companion only
    for (int t = 0; t < SLEN; ++t) __syncthreads();
  }
}

// --------------------------------------------------------------------------
// GEMM accumulate: out += ys_bf16 @ out_w_bf16^T   (out pre-filled with h_ln)
// M=2048, N=1024, K=1024. 512 blocks (2/CU): 64x64 tile, BK=32, 4 waves of
// 32x32. LDS double-buffered, reg-staged (issue-early/write-late), row
// stride padded to 40 bf16 (conflict-free frag reads), XCD-swizzled.
// --------------------------------------------------------------------------
#define LDA 40
__global__ __launch_bounds__(256, 2) void gemm_acc_k(
    const unsigned short* __restrict__ A,
    const unsigned short* __restrict__ B,
    float* __restrict__ out) {
  __shared__ __align__(16) unsigned short Al[2][64 * LDA];
  __shared__ __align__(16) unsigned short Bl[2][64 * LDA];

  const int bid0 = blockIdx.x;
  const int swz = (bid0 & 7) * 64 + (bid0 >> 3);  // 512 % 8 == 0: bijective
  const int bx = swz & 15;   // N tile (1024/64)
  const int by = swz >> 4;   // M tile (2048/64)
  const int tid = threadIdx.x;
  const int wave = tid >> 6, lane = tid & 63;
  const int wr = wave >> 1, wc = wave & 1;
  const int l16 = lane & 15;
  const int kofs = (lane >> 4) * 8;

  const short* Ap = (const short*)A;
  const short* Bp = (const short*)B;

  // staging map: thread covers 8 bf16 at (srow, scol)
  const int srow = tid >> 2;
  const int scol = (tid & 3) * 8;
  const short* ags = Ap + (size_t)(by * 64 + srow) * INDIM + scol;
  const short* bgs = Bp + (size_t)(bx * 64 + srow) * INDIM + scol;
  unsigned short* adst = &Al[0][srow * LDA + scol];   // [buf] offset added below
  unsigned short* bdst = &Bl[0][srow * LDA + scol];

  f32x4 acc[2][2];
  #pragma unroll
  for (int i = 0; i < 2; ++i)
    #pragma unroll
    for (int j = 0; j < 2; ++j)
      acc[i][j] = (f32x4){0.f, 0.f, 0.f, 0.f};

  // prologue: stage k=0 into buf 0
  {
    uint4 ga = *(const uint4*)(ags);
    uint4 gb = *(const uint4*)(bgs);
    *(uint4*)(adst) = ga;
    *(uint4*)(bdst) = gb;
  }
  __syncthreads();

  int buf = 0;
  for (int it = 0; it < 32; ++it) {
    uint4 ga, gb;
    const bool more = (it + 1 < 32);
    if (more) {
      ga = *(const uint4*)(ags + (it + 1) * 32);
      gb = *(const uint4*)(bgs + (it + 1) * 32);
    }
    // compute current tile
    bf16x8 af[2], bfv[2];
    #pragma unroll
    for (int i = 0; i < 2; ++i)
      af[i] = *(const bf16x8*)(&Al[buf][(wr * 32 + i * 16 + l16) * LDA + kofs]);
    #pragma unroll
    for (int j = 0; j < 2; ++j)
      bfv[j] = *(const bf16x8*)(&Bl[buf][(wc * 32 + j * 16 + l16) * LDA + kofs]);
    #pragma unroll
    for (int i = 0; i < 2; ++i)
      #pragma unroll
      for (int j = 0; j < 2; ++j)
        acc[i][j] = __builtin_amdgcn_mfma_f32_16x16x32_bf16(af[i], bfv[j], acc[i][j], 0, 0, 0);
    if (more) {
      *(uint4*)(adst + (buf ^ 1) * 64 * LDA) = ga;
      *(uint4*)(bdst + (buf ^ 1) * 64 * LDA) = gb;
    }
    __syncthreads();
    buf ^= 1;
  }

  const int rq4 = (lane >> 4) * 4;
  #pragma unroll
  for (int i = 0; i < 2; ++i) {
    #pragma unroll
    for (int reg = 0; reg < 4; ++reg) {
      int r = by * 64 + wr * 32 + i * 16 + rq4 + reg;
      #pragma unroll
      for (int j = 0; j < 2; ++j) {
        int n = bx * 64 + wc * 32 + j * 16 + l16;
        size_t idx = (size_t)r * INDIM + n;
        out[idx] += acc[i][j][reg];
      }
    }
  }
}

// --------------------------------------------------------------------------
extern "C" void kernel_launch(void* const* d_in, const int* in_sizes, int n_in,
                              void* d_out, int out_size, void* d_ws, size_t ws_size,
                              hipStream_t stream) {
  const float* h    = (const float*)d_in[0];
  const float* Wy   = (const float*)d_in[1];
  const float* Wq   = (const float*)d_in[2];
  const float* Wk   = (const float*)d_in[3];
  const float* wb   = (const float*)d_in[4];
  const float* outw = (const float*)d_in[5];
  const float* gam  = (const float*)d_in[6];
  const float* bet  = (const float*)d_in[7];
  float* out = (float*)d_out;

  char* ws = (char*)d_ws;
  unsigned short* ys_bf   = (unsigned short*)ws;                                  // 4 MB
  unsigned short* outw_bf = (unsigned short*)(ws + (size_t)2048 * 1024 * 2);      // 2 MB

  scan_prep_k<<<128 + 512 + 2048, 512, 0, stream>>>(h, Wy, Wq, Wk, wb, outw,
                                                    gam, bet, outw_bf, out, ys_bf);
  gemm_acc_k<<<512, 256, 0, stream>>>(ys_bf, outw_bf, out);
}

// Round 8
// 306.919 us; speedup vs baseline: 1.3072x; 1.3072x over previous
//
#include <hip/hip_runtime.h>
#include <hip/hip_bf16.h>

#define SLEN  256
#define BSZ   8
#define NHEAD 16
#define DHEAD 64
#define INDIM 1024
#define LN_EPS 1e-5f

typedef __attribute__((ext_vector_type(4))) float f32x4;
typedef __attribute__((ext_vector_type(8))) short bf16x8;
typedef __attribute__((ext_vector_type(2))) float v2f;

__device__ __forceinline__ int f_as_i(float f) { union { float f; int i; } u; u.f = f; return u.i; }
__device__ __forceinline__ float i_as_f(int i) { union { float f; int i; } u; u.i = i; return u.f; }

__device__ __forceinline__ v2f fma2(v2f a, v2f b, v2f c) {
  return __builtin_elementwise_fma(a, b, c);  // v_pk_fma_f32 on gfx950
}

__device__ inline unsigned short f2bf(float x) {
  __hip_bfloat16 b = __float2bfloat16(x);
  union { __hip_bfloat16 b; unsigned short u; } cv;
  cv.b = b;
  return cv.u;
}

template <int CTRL>
__device__ __forceinline__ float dpp0(float x) {
  return i_as_f(__builtin_amdgcn_update_dpp(0, f_as_i(x), CTRL, 0xF, 0xF, true));
}
// adjacent-lane pair swap: quad_perm [1,0,3,2]
__device__ __forceinline__ float pair_other(float x) { return dpp0<0xB1>(x); }

__device__ __forceinline__ float wave_sum64(float v) {
  v += dpp0<0x111>(v);
  v += dpp0<0x112>(v);
  v += dpp0<0x114>(v);
  v += dpp0<0x118>(v);
  v += dpp0<0x142>(v);  // row_bcast:15
  v += dpp0<0x143>(v);  // row_bcast:31
  return i_as_f(__builtin_amdgcn_readlane(f_as_i(v), 63));
}

// --------------------------------------------------------------------------
// Fused kernel (512 threads/block):
//   blocks 0..127     : SRWM scan, one chain per block, 8 waves
//   blocks 128..639   : out_w fp32->bf16
//   blocks 640..2687  : LN stats + write h_ln into d_out
// --------------------------------------------------------------------------
__global__ __launch_bounds__(512, 1) void scan_prep_k(
    const float* __restrict__ h,
    const float* __restrict__ Wy0,
    const float* __restrict__ Wq0,
    const float* __restrict__ Wk0,
    const float* __restrict__ wb0,
    const float* __restrict__ outw,
    const float* __restrict__ gamma,
    const float* __restrict__ lbeta,
    unsigned short* __restrict__ outw_bf,
    float* __restrict__ outp,
    unsigned short* __restrict__ ys_bf) {
  const int bid = blockIdx.x;
  const int tid = threadIdx.x;

  if (bid >= 128) {
    const int pb = bid - 128;
    if (pb < 512) {
      int i = (pb * 512 + tid) * 4;
      float4 v = *(const float4*)(outw + i);
      ushort4 o;
      o.x = f2bf(v.x); o.y = f2bf(v.y); o.z = f2bf(v.z); o.w = f2bf(v.w);
      *(ushort4*)(outw_bf + i) = o;
    } else {
      int r = pb - 512;  // 0..2047
      const float* row = h + (size_t)r * INDIM;
      float2 v = *(const float2*)(row + tid * 2);
      float s  = v.x + v.y;
      float s2 = v.x * v.x + v.y * v.y;
      s  = wave_sum64(s);
      s2 = wave_sum64(s2);
      __shared__ float ls[8], ls2[8], sstat[2];
      int wvv = tid >> 6;
      if ((tid & 63) == 0) { ls[wvv] = s; ls2[wvv] = s2; }
      __syncthreads();
      if (tid == 0) {
        float S = 0.f, S2 = 0.f;
        #pragma unroll
        for (int i2 = 0; i2 < 8; ++i2) { S += ls[i2]; S2 += ls2[i2]; }
        float mu = S * (1.0f / INDIM);
        float var = S2 * (1.0f / INDIM) - mu * mu;
        sstat[0] = mu;
        sstat[1] = rsqrtf(var + LN_EPS);
      }
      __syncthreads();
      float mu = sstat[0], rs = sstat[1];
      float2 g2 = *(const float2*)(gamma + tid * 2);
      float2 b2 = *(const float2*)(lbeta + tid * 2);
      float2 o;
      o.x = (v.x - mu) * rs * g2.x + b2.x;
      o.y = (v.y - mu) * rs * g2.y + b2.y;
      *(float2*)(outp + (size_t)r * INDIM + tid * 2) = o;
    }
    return;
  }

  // ---------------- SRWM scan: one chain per block, 8 waves ----------------
  // waves 0..5: matrix waves, m=wv>>1 (0=Wy,1=Wq,2=Wk), half=wv&1;
  //   lane pair (2p,2p+1) owns row r=half*32+p; lane&1 picks 32-col half.
  //   All row math on v2f -> v_pk_fma_f32 (2 FLOP/inst).
  // wave 6: wb / beta.  wave 7: x staging (global->LDS, 3 steps ahead).
  const int chain = bid;
  const int b    = chain >> 4;
  const int head = chain & 15;
  const int wv   = __builtin_amdgcn_readfirstlane(tid >> 6);
  const int lane = tid & 63;

  __shared__ __align__(16) float xbuf[3][64];      // x_t in slot t%3
  __shared__ __align__(16) float eqk[2][2][64];    // [t&1][{q,k}][row] = exp(v)
  __shared__ __align__(16) float meta[2][8];       // [t&1][ssub q0,q1,k0,k1, beta0..3]

  const float* xrow0 = h + (size_t)b * INDIM + head * DHEAD;

#define PUBLISH(T, V) {                                                          \
    if (m == 0) {                                                                \
      if (!(lane & 1))                                                           \
        ys_bf[(size_t)((T) * BSZ + b) * INDIM + head * DHEAD + r] = f2bf(V);     \
    } else {                                                                     \
      float e_ = __expf(V);                                                      \
      if (!(lane & 1)) eqk[(T) & 1][m - 1][r] = e_;                              \
      float sh_ = wave_sum64(e_) * 0.5f;                                         \
      if (lane == 0) meta[(T) & 1][(m - 1) * 2 + half] = sh_;                    \
    }                                                                            \
  }

#define PHASE(T, XC, XN) {                                                       \
    const int bp_ = ((T) - 1) & 1;                                               \
    float4 ss4 = *(const float4*)(&meta[bp_][0]);                                \
    float4 bb4 = *(const float4*)(&meta[bp_][4]);                                \
    v2f q2[16], k2[16];                                                          \
    _Pragma("unroll")                                                            \
    for (int g = 0; g < 8; ++g) {                                                \
      float4 qq = *(const float4*)(&eqk[bp_][0][j0 + g * 4]);                    \
      float4 kk = *(const float4*)(&eqk[bp_][1][j0 + g * 4]);                    \
      q2[2 * g] = (v2f){qq.x, qq.y}; q2[2 * g + 1] = (v2f){qq.z, qq.w};          \
      k2[2 * g] = (v2f){kk.x, kk.y}; k2[2 * g + 1] = (v2f){kk.z, kk.w};          \
    }                                                                            \
    if ((T) + 1 < SLEN) {                                                        \
      const float* xsrc_ = &xbuf[((T) + 1) % 3][j0];                             \
      _Pragma("unroll")                                                          \
      for (int g = 0; g < 8; ++g) {                                              \
        float4 x4_ = *(const float4*)(xsrc_ + g * 4);                            \
        XN[2 * g] = (v2f){x4_.x, x4_.y}; XN[2 * g + 1] = (v2f){x4_.z, x4_.w};    \
      }                                                                          \
    }                                                                            \
    v2f dqa = (v2f){0.f, 0.f}, dqb = (v2f){0.f, 0.f};                            \
    v2f dka = (v2f){0.f, 0.f}, dkb = (v2f){0.f, 0.f};                            \
    _Pragma("unroll")                                                            \
    for (int g = 0; g < 16; g += 2) {                                            \
      dqa = fma2(w2[g], q2[g], dqa);                                             \
      dqb = fma2(w2[g + 1], q2[g + 1], dqb);                                     \
      dka = fma2(w2[g], k2[g], dka);                                             \
      dkb = fma2(w2[g + 1], k2[g + 1], dkb);                                     \
    }                                                                            \
    float rq = __fdividef(1.f, ss4.x + ss4.y);                                   \
    float rk = __fdividef(1.f, ss4.z + ss4.w);                                   \
    v2f dqs = dqa + dqb, dks = dka + dkb;                                        \
    float dv = rq * (dqs.x + dqs.y) - rk * (dks.x + dks.y);                      \
    dv += pair_other(dv);                                                        \
    float bet_ = (m == 0) ? bb4.x : ((m == 1) ? bb4.y : bb4.z);                  \
    float c_ = bet_ * dv * rk;                                                   \
    v2f c2 = (v2f){c_, c_};                                                      \
    _Pragma("unroll")                                                            \
    for (int g = 0; g < 16; ++g) w2[g] = fma2(c2, k2[g], w2[g]);                 \
    v2f aa = (v2f){0.f, 0.f}, ab = (v2f){0.f, 0.f};                              \
    _Pragma("unroll")                                                            \
    for (int g = 0; g < 16; g += 2) {                                            \
      aa = fma2(w2[g], XC[g], aa);                                               \
      ab = fma2(w2[g + 1], XC[g + 1], ab);                                       \
    }                                                                            \
    v2f as = aa + ab;                                                            \
    float v_ = as.x + as.y;                                                      \
    v_ += pair_other(v_);                                                        \
    PUBLISH(T, v_);                                                              \
    __syncthreads();                                                             \
  }

  if (wv < 6) {
    const int m    = wv >> 1;
    const int half = wv & 1;
    const int r    = half * 32 + (lane >> 1);
    const int j0   = (lane & 1) * 32;
    const float* Wsel = (m == 0) ? Wy0 : ((m == 1) ? Wq0 : Wk0);
    const float* wrow = Wsel + (size_t)head * DHEAD * DHEAD + (size_t)r * DHEAD + j0;
    v2f w2[16];
    #pragma unroll
    for (int g = 0; g < 8; ++g) {
      float4 t4 = *(const float4*)(wrow + g * 4);
      w2[2 * g] = (v2f){t4.x, t4.y}; w2[2 * g + 1] = (v2f){t4.z, t4.w};
    }
    v2f xA[16], xB[16];
    #pragma unroll
    for (int g = 0; g < 8; ++g) {   // x_0 from global
      float4 t4 = *(const float4*)(xrow0 + j0 + g * 4);
      xA[2 * g] = (v2f){t4.x, t4.y}; xA[2 * g + 1] = (v2f){t4.z, t4.w};
    }
    __syncthreads();  // prologue (wave7 pre-staged x_1, x_2)

    // phase 0: matvec_0 + publish; load xB = x_1
    {
      v2f aa = (v2f){0.f, 0.f}, ab = (v2f){0.f, 0.f};
      #pragma unroll
      for (int g = 0; g < 16; g += 2) {
        aa = fma2(w2[g], xA[g], aa);
        ab = fma2(w2[g + 1], xA[g + 1], ab);
      }
      v2f as = aa + ab;
      float v0 = as.x + as.y;
      v0 += pair_other(v0);
      PUBLISH(0, v0);
      #pragma unroll
      for (int g = 0; g < 8; ++g) {
        float4 x4 = *(const float4*)(&xbuf[1][j0 + g * 4]);
        xB[2 * g] = (v2f){x4.x, x4.y}; xB[2 * g + 1] = (v2f){x4.z, x4.w};
      }
      __syncthreads();
    }
    for (int tt = 1; tt <= 253; tt += 2) {
      PHASE(tt, xB, xA);
      PHASE(tt + 1, xA, xB);
    }
    PHASE(255, xB, xA);
  } else if (wv == 6) {
    // wb / beta wave
    const float* wbrow = wb0 + (size_t)head * DHEAD * 4 + lane * 4;
    float4 wbv = *(const float4*)wbrow;
    const float* xl = h + (size_t)b * INDIM + head * DHEAD + lane;
    float xv = xl[0];
    float xn = xl[(size_t)BSZ * INDIM];
    float b3prev = 0.f;
    __syncthreads();  // prologue

    {  // phase 0: beta_0
      float p0 = wave_sum64(wbv.x * xv);
      float p1 = wave_sum64(wbv.y * xv);
      float p2 = wave_sum64(wbv.z * xv);
      float p3 = wave_sum64(wbv.w * xv);
      float b0 = __fdividef(1.f, 1.f + __expf(-p0));
      float b1 = __fdividef(1.f, 1.f + __expf(-p1));
      float b2 = __fdividef(1.f, 1.f + __expf(-p2));
      float b3 = __fdividef(1.f, 1.f + __expf(-p3));
      if (lane == 0) *(float4*)(&meta[0][4]) = (float4){b0, b1, b2, b3};
      b3prev = b3;
      xv = xn;
      xn = xl[(size_t)2 * BSZ * INDIM];
      __syncthreads();
    }
    for (int t = 1; t < SLEN; ++t) {
      const int bp = (t - 1) & 1;
      float4 ss4 = *(const float4*)(&meta[bp][0]);
      float eq = eqk[bp][0][lane];
      float ek = eqk[bp][1][lane];
      float rq = __fdividef(1.f, ss4.x + ss4.y);
      float rk = __fdividef(1.f, ss4.z + ss4.w);
      float qv = rq * eq, kv = rk * ek;
      float qmk = qv - kv;
      float g0 = wave_sum64(wbv.x * qmk);
      float g1 = wave_sum64(wbv.y * qmk);
      float g2 = wave_sum64(wbv.z * qmk);
      float g3 = wave_sum64(wbv.w * qmk);
      float cl = b3prev * kv;
      wbv.x += cl * g0; wbv.y += cl * g1; wbv.z += cl * g2; wbv.w += cl * g3;
      // beta_t with updated wb and x_t
      float p0 = wave_sum64(wbv.x * xv);
      float p1 = wave_sum64(wbv.y * xv);
      float p2 = wave_sum64(wbv.z * xv);
      float p3 = wave_sum64(wbv.w * xv);
      float b0 = __fdividef(1.f, 1.f + __expf(-p0));
      float b1 = __fdividef(1.f, 1.f + __expf(-p1));
      float b2 = __fdividef(1.f, 1.f + __expf(-p2));
      float b3 = __fdividef(1.f, 1.f + __expf(-p3));
      if (lane == 0) *(float4*)(&meta[t & 1][4]) = (float4){b0, b1, b2, b3};
      b3prev = b3;
      xv = xn;
      if (t + 2 < SLEN) xn = xl[(size_t)(t + 2) * BSZ * INDIM];
      __syncthreads();
    }
  } else {
    // wave 7: x staging, 3 steps ahead, triple-buffered
    xbuf[1][lane] = xrow0[(size_t)BSZ * INDIM + lane];          // x_1
    xbuf[2][lane] = xrow0[(size_t)2 * BSZ * INDIM + lane];      // x_2
    float g1 = xrow0[(size_t)3 * BSZ * INDIM + lane];           // x_3
    __syncthreads();  // prologue

    for (int t = 0; t < SLEN; ++t) {
      if (t + 3 < SLEN) xbuf[t % 3][lane] = g1;                 // x_{t+3}
      if (t + 4 < SLEN) g1 = xrow0[(size_t)(t + 4) * BSZ * INDIM + lane];
      __syncthreads();
    }
  }
#undef PHASE
#undef PUBLISH
}

// --------------------------------------------------------------------------
// GEMM accumulate: out += scale * (ys_bf16 @ out_w_bf16^T)
// (out pre-filled with h_ln). Launched twice: scale=1e-38 probe (full
// traffic, result-invisible) then scale=1 real -- to expose the GEMM's true
// duration in the top-5 dispatch table.
// --------------------------------------------------------------------------
#define LDA 40
__global__ __launch_bounds__(256, 2) void gemm_acc_k(
    const unsigned short* __restrict__ A,
    const unsigned short* __restrict__ B,
    float* __restrict__ out,
    float scale) {
  __shared__ __align__(16) unsigned short Al[2][64 * LDA];
  __shared__ __align__(16) unsigned short Bl[2][64 * LDA];

  const int bid0 = blockIdx.x;
  const int swz = (bid0 & 7) * 64 + (bid0 >> 3);  // 512 % 8 == 0: bijective
  const int bx = swz & 15;   // N tile (1024/64)
  const int by = swz >> 4;   // M tile (2048/64)
  const int tid = threadIdx.x;
  const int wave = tid >> 6, lane = tid & 63;
  const int wr = wave >> 1, wc = wave & 1;
  const int l16 = lane & 15;
  const int kofs = (lane >> 4) * 8;

  const short* Ap = (const short*)A;
  const short* Bp = (const short*)B;

  const int srow = tid >> 2;
  const int scol = (tid & 3) * 8;
  const short* ags = Ap + (size_t)(by * 64 + srow) * INDIM + scol;
  const short* bgs = Bp + (size_t)(bx * 64 + srow) * INDIM + scol;
  unsigned short* adst = &Al[0][srow * LDA + scol];
  unsigned short* bdst = &Bl[0][srow * LDA + scol];

  f32x4 acc[2][2];
  #pragma unroll
  for (int i = 0; i < 2; ++i)
    #pragma unroll
    for (int j = 0; j < 2; ++j)
      acc[i][j] = (f32x4){0.f, 0.f, 0.f, 0.f};

  {
    uint4 ga = *(const uint4*)(ags);
    uint4 gb = *(const uint4*)(bgs);
    *(uint4*)(adst) = ga;
    *(uint4*)(bdst) = gb;
  }
  __syncthreads();

  int buf = 0;
  for (int it = 0; it < 32; ++it) {
    uint4 ga, gb;
    const bool more = (it + 1 < 32);
    if (more) {
      ga = *(const uint4*)(ags + (it + 1) * 32);
      gb = *(const uint4*)(bgs + (it + 1) * 32);
    }
    bf16x8 af[2], bfv[2];
    #pragma unroll
    for (int i = 0; i < 2; ++i)
      af[i] = *(const bf16x8*)(&Al[buf][(wr * 32 + i * 16 + l16) * LDA + kofs]);
    #pragma unroll
    for (int j = 0; j < 2; ++j)
      bfv[j] = *(const bf16x8*)(&Bl[buf][(wc * 32 + j * 16 + l16) * LDA + kofs]);
    #pragma unroll
    for (int i = 0; i < 2; ++i)
      #pragma unroll
      for (int j = 0; j < 2; ++j)
        acc[i][j] = __builtin_amdgcn_mfma_f32_16x16x32_bf16(af[i], bfv[j], acc[i][j], 0, 0, 0);
    if (more) {
      *(uint4*)(adst + (buf ^ 1) * 64 * LDA) = ga;
      *(uint4*)(bdst + (buf ^ 1) * 64 * LDA) = gb;
    }
    __syncthreads();
    buf ^= 1;
  }

  const int rq4 = (lane >> 4) * 4;
  #pragma unroll
  for (int i = 0; i < 2; ++i) {
    #pragma unroll
    for (int reg = 0; reg < 4; ++reg) {
      int r = by * 64 + wr * 32 + i * 16 + rq4 + reg;
      #pragma unroll
      for (int j = 0; j < 2; ++j) {
        int n = bx * 64 + wc * 32 + j * 16 + l16;
        size_t idx = (size_t)r * INDIM + n;
        out[idx] += acc[i][j][reg] * scale;
      }
    }
  }
}

// --------------------------------------------------------------------------
extern "C" void kernel_launch(void* const* d_in, const int* in_sizes, int n_in,
                              void* d_out, int out_size, void* d_ws, size_t ws_size,
                              hipStream_t stream) {
  const float* h    = (const float*)d_in[0];
  const float* Wy   = (const float*)d_in[1];
  const float* Wq   = (const float*)d_in[2];
  const float* Wk   = (const float*)d_in[3];
  const float* wb   = (const float*)d_in[4];
  const float* outw = (const float*)d_in[5];
  const float* gam  = (const float*)d_in[6];
  const float* bet  = (const float*)d_in[7];
  float* out = (float*)d_out;

  char* ws = (char*)d_ws;
  unsigned short* ys_bf   = (unsigned short*)ws;                                  // 4 MB
  unsigned short* outw_bf = (unsigned short*)(ws + (size_t)2048 * 1024 * 2);      // 2 MB

  scan_prep_k<<<128 + 512 + 2048, 512, 0, stream>>>(h, Wy, Wq, Wk, wb, outw,
                                                    gam, bet, outw_bf, out, ys_bf);
  gemm_acc_k<<<512, 256, 0, stream>>>(ys_bf, outw_bf, out, 1e-38f);  // probe
  gemm_acc_k<<<512, 256, 0, stream>>>(ys_bf, outw_bf, out, 1.0f);    // real
}

// Round 9
// 293.064 us; speedup vs baseline: 1.3690x; 1.0473x over previous
//
#include <hip/hip_runtime.h>
#include <hip/hip_bf16.h>

#define SLEN  256
#define BSZ   8
#define NHEAD 16
#define DHEAD 64
#define INDIM 1024
#define LN_EPS 1e-5f

typedef __attribute__((ext_vector_type(4))) float f32x4;
typedef __attribute__((ext_vector_type(8))) short bf16x8;

__device__ __forceinline__ int f_as_i(float f) { union { float f; int i; } u; u.f = f; return u.i; }
__device__ __forceinline__ float i_as_f(int i) { union { float f; int i; } u; u.i = i; return u.f; }

__device__ __forceinline__ f32x4 fma4(f32x4 a, f32x4 b, f32x4 c) {
  return __builtin_elementwise_fma(a, b, c);  // 2x v_pk_fma_f32
}
__device__ __forceinline__ float hsum4(f32x4 a) { return (a.x + a.y) + (a.z + a.w); }

__device__ inline unsigned short f2bf(float x) {
  __hip_bfloat16 b = __float2bfloat16(x);
  union { __hip_bfloat16 b; unsigned short u; } cv;
  cv.b = b;
  return cv.u;
}

template <int CTRL>
__device__ __forceinline__ float dpp0(float x) {
  return i_as_f(__builtin_amdgcn_update_dpp(0, f_as_i(x), CTRL, 0xF, 0xF, true));
}
// adjacent-lane pair swap: quad_perm [1,0,3,2]
__device__ __forceinline__ float pair_other(float x) { return dpp0<0xB1>(x); }

__device__ __forceinline__ float wave_sum64(float v) {
  v += dpp0<0x111>(v);
  v += dpp0<0x112>(v);
  v += dpp0<0x114>(v);
  v += dpp0<0x118>(v);
  v += dpp0<0x142>(v);  // row_bcast:15
  v += dpp0<0x143>(v);  // row_bcast:31
  return i_as_f(__builtin_amdgcn_readlane(f_as_i(v), 63));
}

// --------------------------------------------------------------------------
// Fused kernel (512 threads/block):
//   blocks 0..127     : SRWM scan, one chain per block, 8 waves
//   blocks 128..639   : out_w fp32->bf16
//   blocks 640..2687  : LN stats + write h_ln into d_out
// --------------------------------------------------------------------------
__global__ __launch_bounds__(512, 1) void scan_prep_k(
    const float* __restrict__ h,
    const float* __restrict__ Wy0,
    const float* __restrict__ Wq0,
    const float* __restrict__ Wk0,
    const float* __restrict__ wb0,
    const float* __restrict__ outw,
    const float* __restrict__ gamma,
    const float* __restrict__ lbeta,
    unsigned short* __restrict__ outw_bf,
    float* __restrict__ outp,
    unsigned short* __restrict__ ys_bf) {
  const int bid = blockIdx.x;
  const int tid = threadIdx.x;

  if (bid >= 128) {
    const int pb = bid - 128;
    if (pb < 512) {
      int i = (pb * 512 + tid) * 4;
      float4 v = *(const float4*)(outw + i);
      ushort4 o;
      o.x = f2bf(v.x); o.y = f2bf(v.y); o.z = f2bf(v.z); o.w = f2bf(v.w);
      *(ushort4*)(outw_bf + i) = o;
    } else {
      int r = pb - 512;  // 0..2047
      const float* row = h + (size_t)r * INDIM;
      float2 v = *(const float2*)(row + tid * 2);
      float s  = v.x + v.y;
      float s2 = v.x * v.x + v.y * v.y;
      s  = wave_sum64(s);
      s2 = wave_sum64(s2);
      __shared__ float ls[8], ls2[8], sstat[2];
      int wvv = tid >> 6;
      if ((tid & 63) == 0) { ls[wvv] = s; ls2[wvv] = s2; }
      __syncthreads();
      if (tid == 0) {
        float S = 0.f, S2 = 0.f;
        #pragma unroll
        for (int i2 = 0; i2 < 8; ++i2) { S += ls[i2]; S2 += ls2[i2]; }
        float mu = S * (1.0f / INDIM);
        float var = S2 * (1.0f / INDIM) - mu * mu;
        sstat[0] = mu;
        sstat[1] = rsqrtf(var + LN_EPS);
      }
      __syncthreads();
      float mu = sstat[0], rs = sstat[1];
      float2 g2 = *(const float2*)(gamma + tid * 2);
      float2 b2 = *(const float2*)(lbeta + tid * 2);
      float2 o;
      o.x = (v.x - mu) * rs * g2.x + b2.x;
      o.y = (v.y - mu) * rs * g2.y + b2.y;
      *(float2*)(outp + (size_t)r * INDIM + tid * 2) = o;
    }
    return;
  }

  // ---------------- SRWM scan: one chain per block, 8 waves ----------------
  // waves 0..5: matrix waves, m=wv>>1 (0=Wy,1=Wq,2=Wk), half=wv&1;
  //   lane pair (2p,2p+1) owns row r=half*32+p; lane&1 picks 32-col half.
  //   Phase order (latency-hiding): issue LDS reads -> matvec with OLD w
  //   (regs) -> dv/ekx/update -> v = mv + c*(ek.x) -> publish. The rank-1
  //   identity (W+c k^T)x = Wx + c(k.x) makes this exact.
  // wave 6: wb / beta.  wave 7: x staging (global->LDS, 3 steps ahead).
  const int chain = bid;
  const int b    = chain >> 4;
  const int head = chain & 15;
  const int wv   = __builtin_amdgcn_readfirstlane(tid >> 6);
  const int lane = tid & 63;

  __shared__ __align__(16) float xbuf[3][64];      // x_t in slot t%3
  __shared__ __align__(16) float eqk[2][2][64];    // [t&1][{q,k}][row] = exp(v)
  __shared__ __align__(16) float meta[2][8];       // [t&1][ssub q0,q1,k0,k1, beta0..3]

  const float* xrow0 = h + (size_t)b * INDIM + head * DHEAD;

#define PUBLISH(T, V) {                                                          \
    if (m == 0) {                                                                \
      if (!(lane & 1))                                                           \
        ys_bf[(size_t)((T) * BSZ + b) * INDIM + head * DHEAD + r] = f2bf(V);     \
    } else {                                                                     \
      float e_ = __expf(V);                                                      \
      if (!(lane & 1)) eqk[(T) & 1][m - 1][r] = e_;                              \
      float sh_ = wave_sum64(e_) * 0.5f;                                         \
      if (lane == 0) meta[(T) & 1][(m - 1) * 2 + half] = sh_;                    \
    }                                                                            \
  }

#define PHASE(T, XC, XN) {                                                       \
    const int bp_ = ((T) - 1) & 1;                                               \
    const f32x4* eq4_ = (const f32x4*)(&eqk[bp_][0][j0]);                        \
    const f32x4* ek4_ = (const f32x4*)(&eqk[bp_][1][j0]);                        \
    f32x4 q4[8], k4[8];                                                          \
    _Pragma("unroll")                                                            \
    for (int g = 0; g < 8; ++g) { q4[g] = eq4_[g]; k4[g] = ek4_[g]; }            \
    float4 ss4 = *(const float4*)(&meta[bp_][0]);                                \
    float4 bb4 = *(const float4*)(&meta[bp_][4]);                                \
    if ((T) + 1 < SLEN) {                                                        \
      const f32x4* xs_ = (const f32x4*)(&xbuf[((T) + 1) % 3][j0]);               \
      _Pragma("unroll")                                                          \
      for (int g = 0; g < 8; ++g) XN[g] = xs_[g];                                \
    }                                                                            \
    f32x4 mva = (f32x4){0.f, 0.f, 0.f, 0.f};                                     \
    f32x4 mvb = (f32x4){0.f, 0.f, 0.f, 0.f};                                     \
    _Pragma("unroll")                                                            \
    for (int g = 0; g < 8; g += 2) {                                             \
      mva = fma4(w4[g], XC[g], mva);                                             \
      mvb = fma4(w4[g + 1], XC[g + 1], mvb);                                     \
    }                                                                            \
    f32x4 dqa = (f32x4){0.f, 0.f, 0.f, 0.f};                                     \
    f32x4 dka = (f32x4){0.f, 0.f, 0.f, 0.f};                                     \
    f32x4 exa = (f32x4){0.f, 0.f, 0.f, 0.f};                                     \
    _Pragma("unroll")                                                            \
    for (int g = 0; g < 8; ++g) {                                                \
      dqa = fma4(w4[g], q4[g], dqa);                                             \
      dka = fma4(w4[g], k4[g], dka);                                             \
      exa = fma4(k4[g], XC[g], exa);                                             \
    }                                                                            \
    float rq = __fdividef(1.f, ss4.x + ss4.y);                                   \
    float rk = __fdividef(1.f, ss4.z + ss4.w);                                   \
    float dv = rq * hsum4(dqa) - rk * hsum4(dka);                                \
    dv += pair_other(dv);                                                        \
    float bet_ = (m == 0) ? bb4.x : ((m == 1) ? bb4.y : bb4.z);                  \
    float c_ = bet_ * dv * rk;                                                   \
    f32x4 c4_ = (f32x4){c_, c_, c_, c_};                                         \
    _Pragma("unroll")                                                            \
    for (int g = 0; g < 8; ++g) w4[g] = fma4(c4_, k4[g], w4[g]);                 \
    float A_ = hsum4(mva + mvb); A_ += pair_other(A_);                           \
    float B_ = hsum4(exa);       B_ += pair_other(B_);                           \
    float v_ = A_ + c_ * B_;                                                     \
    PUBLISH(T, v_);                                                              \
    __syncthreads();                                                             \
  }

  if (wv < 6) {
    const int m    = wv >> 1;
    const int half = wv & 1;
    const int r    = half * 32 + (lane >> 1);
    const int j0   = (lane & 1) * 32;
    const float* Wsel = (m == 0) ? Wy0 : ((m == 1) ? Wq0 : Wk0);
    const float* wrow = Wsel + (size_t)head * DHEAD * DHEAD + (size_t)r * DHEAD + j0;
    f32x4 w4[8];
    #pragma unroll
    for (int g = 0; g < 8; ++g) w4[g] = *(const f32x4*)(wrow + g * 4);
    f32x4 xA[8], xB[8];
    #pragma unroll
    for (int g = 0; g < 8; ++g) xA[g] = *(const f32x4*)(xrow0 + j0 + g * 4);
    __syncthreads();  // prologue (wave7 pre-staged x_1, x_2)

    // phase 0: read x_1 early, matvec_0, publish
    {
      const f32x4* xs = (const f32x4*)(&xbuf[1][j0]);
      #pragma unroll
      for (int g = 0; g < 8; ++g) xB[g] = xs[g];
      f32x4 aa = (f32x4){0.f, 0.f, 0.f, 0.f};
      f32x4 ab = (f32x4){0.f, 0.f, 0.f, 0.f};
      #pragma unroll
      for (int g = 0; g < 8; g += 2) {
        aa = fma4(w4[g], xA[g], aa);
        ab = fma4(w4[g + 1], xA[g + 1], ab);
      }
      float v0 = hsum4(aa + ab);
      v0 += pair_other(v0);
      PUBLISH(0, v0);
      __syncthreads();
    }
    for (int tt = 1; tt <= 253; tt += 2) {
      PHASE(tt, xB, xA);
      PHASE(tt + 1, xA, xB);
    }
    PHASE(255, xB, xA);
  } else if (wv == 6) {
    // wb / beta wave
    const float* wbrow = wb0 + (size_t)head * DHEAD * 4 + lane * 4;
    float4 wbv = *(const float4*)wbrow;
    const float* xl = h + (size_t)b * INDIM + head * DHEAD + lane;
    float xv = xl[0];
    float xn = xl[(size_t)BSZ * INDIM];
    float b3prev = 0.f;
    __syncthreads();  // prologue

    {  // phase 0: beta_0
      float p0 = wave_sum64(wbv.x * xv);
      float p1 = wave_sum64(wbv.y * xv);
      float p2 = wave_sum64(wbv.z * xv);
      float p3 = wave_sum64(wbv.w * xv);
      float b0 = __fdividef(1.f, 1.f + __expf(-p0));
      float b1 = __fdividef(1.f, 1.f + __expf(-p1));
      float b2 = __fdividef(1.f, 1.f + __expf(-p2));
      float b3 = __fdividef(1.f, 1.f + __expf(-p3));
      if (lane == 0) *(float4*)(&meta[0][4]) = (float4){b0, b1, b2, b3};
      b3prev = b3;
      xv = xn;
      xn = xl[(size_t)2 * BSZ * INDIM];
      __syncthreads();
    }
    for (int t = 1; t < SLEN; ++t) {
      const int bp = (t - 1) & 1;
      float4 ss4 = *(const float4*)(&meta[bp][0]);
      float eq = eqk[bp][0][lane];
      float ek = eqk[bp][1][lane];
      float rq = __fdividef(1.f, ss4.x + ss4.y);
      float rk = __fdividef(1.f, ss4.z + ss4.w);
      float qv = rq * eq, kv = rk * ek;
      float qmk = qv - kv;
      float g0 = wave_sum64(wbv.x * qmk);
      float g1 = wave_sum64(wbv.y * qmk);
      float g2 = wave_sum64(wbv.z * qmk);
      float g3 = wave_sum64(wbv.w * qmk);
      float cl = b3prev * kv;
      wbv.x += cl * g0; wbv.y += cl * g1; wbv.z += cl * g2; wbv.w += cl * g3;
      // beta_t with updated wb and x_t
      float p0 = wave_sum64(wbv.x * xv);
      float p1 = wave_sum64(wbv.y * xv);
      float p2 = wave_sum64(wbv.z * xv);
      float p3 = wave_sum64(wbv.w * xv);
      float b0 = __fdividef(1.f, 1.f + __expf(-p0));
      float b1 = __fdividef(1.f, 1.f + __expf(-p1));
      float b2 = __fdividef(1.f, 1.f + __expf(-p2));
      float b3 = __fdividef(1.f, 1.f + __expf(-p3));
      if (lane == 0) *(float4*)(&meta[t & 1][4]) = (float4){b0, b1, b2, b3};
      b3prev = b3;
      xv = xn;
      if (t + 2 < SLEN) xn = xl[(size_t)(t + 2) * BSZ * INDIM];
      __syncthreads();
    }
  } else {
    // wave 7: x staging, 3 steps ahead, triple-buffered
    xbuf[1][lane] = xrow0[(size_t)BSZ * INDIM + lane];          // x_1
    xbuf[2][lane] = xrow0[(size_t)2 * BSZ * INDIM + lane];      // x_2
    float g1 = xrow0[(size_t)3 * BSZ * INDIM + lane];           // x_3
    __syncthreads();  // prologue

    for (int t = 0; t < SLEN; ++t) {
      if (t + 3 < SLEN) xbuf[t % 3][lane] = g1;                 // x_{t+3}
      if (t + 4 < SLEN) g1 = xrow0[(size_t)(t + 4) * BSZ * INDIM + lane];
      __syncthreads();
    }
  }
#undef PHASE
#undef PUBLISH
}

// --------------------------------------------------------------------------
// GEMM accumulate: out += ys_bf16 @ out_w_bf16^T  (out pre-filled with h_ln)
// M=2048, N=1024, K=1024. 512 blocks (2/CU): 64x64 tile, BK=64 (16 iters,
// 8 MFMA/iter/wave), LDS double-buffered reg-staged, padded stride, XCD swz.
// --------------------------------------------------------------------------
#define GLDA 72
__global__ __launch_bounds__(256, 2) void gemm_acc_k(
    const unsigned short* __restrict__ A,
    const unsigned short* __restrict__ B,
    float* __restrict__ out) {
  __shared__ __align__(16) unsigned short Al[2][64 * GLDA];
  __shared__ __align__(16) unsigned short Bl[2][64 * GLDA];

  const int bid0 = blockIdx.x;
  const int swz = (bid0 & 7) * 64 + (bid0 >> 3);  // 512 % 8 == 0: bijective
  const int bx = swz & 15;   // N tile (1024/64)
  const int by = swz >> 4;   // M tile (2048/64)
  const int tid = threadIdx.x;
  const int wave = tid >> 6, lane = tid & 63;
  const int wr = wave >> 1, wc = wave & 1;
  const int l16 = lane & 15;
  const int kofs = (lane >> 4) * 8;

  const short* Ap = (const short*)A;
  const short* Bp = (const short*)B;

  // staging: thread covers 32B at (srow, scol) and (srow, scol+8)
  const int srow = tid >> 2;
  const int scol = (tid & 3) * 16;
  const short* ags = Ap + (size_t)(by * 64 + srow) * INDIM + scol;
  const short* bgs = Bp + (size_t)(bx * 64 + srow) * INDIM + scol;
  unsigned short* adst = &Al[0][srow * GLDA + scol];
  unsigned short* bdst = &Bl[0][srow * GLDA + scol];

  f32x4 acc[2][2];
  #pragma unroll
  for (int i = 0; i < 2; ++i)
    #pragma unroll
    for (int j = 0; j < 2; ++j)
      acc[i][j] = (f32x4){0.f, 0.f, 0.f, 0.f};

  {  // prologue: stage k-chunk 0
    uint4 a0 = *(const uint4*)(ags);
    uint4 a1 = *(const uint4*)(ags + 8);
    uint4 b0 = *(const uint4*)(bgs);
    uint4 b1 = *(const uint4*)(bgs + 8);
    *(uint4*)(adst) = a0;
    *(uint4*)(adst + 8) = a1;
    *(uint4*)(bdst) = b0;
    *(uint4*)(bdst + 8) = b1;
  }
  __syncthreads();

  int buf = 0;
  for (int it = 0; it < 16; ++it) {
    uint4 a0, a1, b0, b1;
    const bool more = (it + 1 < 16);
    if (more) {
      const int ko = (it + 1) * 64;
      a0 = *(const uint4*)(ags + ko);
      a1 = *(const uint4*)(ags + ko + 8);
      b0 = *(const uint4*)(bgs + ko);
      b1 = *(const uint4*)(bgs + ko + 8);
    }
    #pragma unroll
    for (int ks = 0; ks < 2; ++ks) {
      bf16x8 af[2], bfv[2];
      #pragma unroll
      for (int i = 0; i < 2; ++i)
        af[i] = *(const bf16x8*)(&Al[buf][(wr * 32 + i * 16 + l16) * GLDA + ks * 32 + kofs]);
      #pragma unroll
      for (int j = 0; j < 2; ++j)
        bfv[j] = *(const bf16x8*)(&Bl[buf][(wc * 32 + j * 16 + l16) * GLDA + ks * 32 + kofs]);
      #pragma unroll
      for (int i = 0; i < 2; ++i)
        #pragma unroll
        for (int j = 0; j < 2; ++j)
          acc[i][j] = __builtin_amdgcn_mfma_f32_16x16x32_bf16(af[i], bfv[j], acc[i][j], 0, 0, 0);
    }
    if (more) {
      unsigned short* ad = adst + (buf ^ 1) * 64 * GLDA;
      unsigned short* bd = bdst + (buf ^ 1) * 64 * GLDA;
      *(uint4*)(ad) = a0;
      *(uint4*)(ad + 8) = a1;
      *(uint4*)(bd) = b0;
      *(uint4*)(bd + 8) = b1;
    }
    __syncthreads();
    buf ^= 1;
  }

  const int rq4 = (lane >> 4) * 4;
  #pragma unroll
  for (int i = 0; i < 2; ++i) {
    #pragma unroll
    for (int reg = 0; reg < 4; ++reg) {
      int r = by * 64 + wr * 32 + i * 16 + rq4 + reg;
      #pragma unroll
      for (int j = 0; j < 2; ++j) {
        int n = bx * 64 + wc * 32 + j * 16 + l16;
        size_t idx = (size_t)r * INDIM + n;
        out[idx] += acc[i][j][reg];
      }
    }
  }
}

// --------------------------------------------------------------------------
extern "C" void kernel_launch(void* const* d_in, const int* in_sizes, int n_in,
                              void* d_out, int out_size, void* d_ws, size_t ws_size,
                              hipStream_t stream) {
  const float* h    = (const float*)d_in[0];
  const float* Wy   = (const float*)d_in[1];
  const float* Wq   = (const float*)d_in[2];
  const float* Wk   = (const float*)d_in[3];
  const float* wb   = (const float*)d_in[4];
  const float* outw = (const float*)d_in[5];
  const float* gam  = (const float*)d_in[6];
  const float* bet  = (const float*)d_in[7];
  float* out = (float*)d_out;

  char* ws = (char*)d_ws;
  unsigned short* ys_bf   = (unsigned short*)ws;                                  // 4 MB
  unsigned short* outw_bf = (unsigned short*)(ws + (size_t)2048 * 1024 * 2);      // 2 MB

  scan_prep_k<<<128 + 512 + 2048, 512, 0, stream>>>(h, Wy, Wq, Wk, wb, outw,
                                                    gam, bet, outw_bf, out, ys_bf);
  gemm_acc_k<<<512, 256, 0, stream>>>(ys_bf, outw_bf, out);
}